// Round 8
// baseline (288.541 us; speedup 1.0000x reference)
//
#include <hip/hip_runtime.h>

// B=32, C=64, H=W=112. Per-sample 3x3 convs via bf16 MFMA implicit GEMM on a
// ZERO-PADDED bf16 image: layout [b][p][ci], p = y*113 + x, col 112 of each row
// is a shared zero border (serves x=-1 of next row and x=112 of this row);
// slots p=-3..-1 are zero rows used when y+dy is out of range.
// Conv block: 16x16 output tile, 4 waves x 4 rows. All 9-tap weights in LDS
// (73.7KB, staged once, ONE barrier); k-loop = pure {ds_read A, global B, MFMA},
// no barriers, no masks, no conversions -> compiler free to pipeline.
#define HW   112
#define HW2  12544
#define CH   64
#define NB   32
#define PW   113            // padded row stride in pixels
#define SS   12672          // pixel slots per sample (need 12659)
#define NPC  (NB*HW2)

using u16 = unsigned short;
typedef __attribute__((ext_vector_type(8))) short bf16x8;   // 8 bf16 = 4 VGPRs
typedef __attribute__((ext_vector_type(4))) float f32x4;

__device__ __forceinline__ float b2f(u16 u) {
    union { unsigned int i; float f; } c;
    c.i = ((unsigned int)u) << 16;
    return c.f;
}
__device__ __forceinline__ u16 f2b(float f) {
    union { float f; unsigned int i; } c;
    c.f = f;
    unsigned int x = c.i;
    x += 0x7fffu + ((x >> 16) & 1u);   // RNE
    return (u16)(x >> 16);
}

// img: padded bf16 image. wt: bf16 [b][tap][co][ci]. outp: padded bf16 image.
// sums: 128 floats (sum, sumsq) accumulated atomically.
__global__ __launch_bounds__(256, 2)
void conv_mfma(const u16* __restrict__ img, const u16* __restrict__ wt,
               u16* __restrict__ outp, float* __restrict__ sums)
{
    __shared__ u16 wl[9 * 4096];         // 73728 B: [tap][h][kg][co][8ci]
    // XCD swizzle: 1568 blocks = 8 XCD x 196; consecutive ids same sample.
    const int bid = (int)blockIdx.x;
    const int sid = (bid & 7) * 196 + (bid >> 3);
    const int b   = sid / 49;
    const int rem = sid - b * 49;
    const int ty0 = (rem / 7) * 16, tx0 = (rem % 7) * 16;
    const int tid  = threadIdx.x;
    const int lane = tid & 63, wave = tid >> 6;
    const int px = lane & 15, kg = lane >> 4;
    const int y0 = wave * 4;

    // ---- stage ALL weights once: wl[tap][h][kg][co][8ci] ----
    const u16* wtb = wt + (size_t)b * 9 * 4096;
    const int wco = tid & 63, wkg = tid >> 6;
#pragma unroll
    for (int c = 0; c < 9; ++c)
#pragma unroll
        for (int hh = 0; hh < 2; ++hh) {
            bf16x8 v = *(const bf16x8*)(wtb + c * 4096 + wco * 64 + hh * 32 + wkg * 8);
            *(bf16x8*)(wl + c * 4096 + hh * 2048 + tid * 8) = v;
        }
    __syncthreads();

    // ---- row pointers for the 6 rows this wave can touch (y0-1 .. y0+4) ----
    const u16* base = img + ((size_t)b * SS + 3) * 64;
    const u16* rp[6];
#pragma unroll
    for (int k = 0; k < 6; ++k) {
        int yy = ty0 + y0 + k - 1;
        int pp = ((unsigned)yy < (unsigned)HW) ? yy * PW + tx0 + px - 1 : -3;
        rp[k] = base + (ptrdiff_t)pp * 64 + kg * 8;   // p=-3..-1 are zero slots
    }

    f32x4 acc[4][4];
#pragma unroll
    for (int r = 0; r < 4; ++r)
#pragma unroll
        for (int m = 0; m < 4; ++m) acc[r][m] = (f32x4)0.f;

    // ---- 9 taps, fully unrolled, zero barriers ----
#pragma unroll
    for (int tap = 0; tap < 9; ++tap) {
        const int dy = tap / 3, dx = tap % 3;
        bf16x8 Bf[4][2];
#pragma unroll
        for (int r = 0; r < 4; ++r) {
            const u16* bp = rp[r + dy] + dx * 64;
            Bf[r][0] = *(const bf16x8*)(bp);
            Bf[r][1] = *(const bf16x8*)(bp + 32);
        }
        bf16x8 Af[4][2];
#pragma unroll
        for (int m = 0; m < 4; ++m) {
            Af[m][0] = *(const bf16x8*)(wl + tap * 4096 +    0 + kg * 512 + (m * 16 + px) * 8);
            Af[m][1] = *(const bf16x8*)(wl + tap * 4096 + 2048 + kg * 512 + (m * 16 + px) * 8);
        }
#pragma unroll
        for (int hh = 0; hh < 2; ++hh)
#pragma unroll
            for (int r = 0; r < 4; ++r)
#pragma unroll
                for (int m = 0; m < 4; ++m)
                    acc[r][m] = __builtin_amdgcn_mfma_f32_16x16x32_bf16(Af[m][hh], Bf[r][hh], acc[r][m], 0, 0, 0);
    }

    // ---- epilogue: store to padded outp + BN batch-stat partials ----
    float s_[4][4], sq[4][4];
#pragma unroll
    for (int m = 0; m < 4; ++m)
#pragma unroll
        for (int q = 0; q < 4; ++q) { s_[m][q] = 0.f; sq[m][q] = 0.f; }

    u16* ob = outp + ((size_t)b * SS + 3 + (size_t)(ty0 + y0) * PW + tx0 + px) * 64 + kg * 4;
#pragma unroll
    for (int r = 0; r < 4; ++r) {
#pragma unroll
        for (int m = 0; m < 4; ++m) {
            float v0 = acc[r][m][0], v1 = acc[r][m][1], v2 = acc[r][m][2], v3 = acc[r][m][3];
            s_[m][0] += v0; s_[m][1] += v1; s_[m][2] += v2; s_[m][3] += v3;
            sq[m][0] += v0 * v0; sq[m][1] += v1 * v1; sq[m][2] += v2 * v2; sq[m][3] += v3 * v3;
            uint2 pk;
            pk.x = ((unsigned)f2b(v1) << 16) | f2b(v0);
            pk.y = ((unsigned)f2b(v3) << 16) | f2b(v2);
            *(uint2*)(ob + (size_t)r * PW * 64 + m * 16) = pk;
        }
    }
#pragma unroll
    for (int off = 1; off < 16; off <<= 1) {
#pragma unroll
        for (int m = 0; m < 4; ++m)
#pragma unroll
            for (int q = 0; q < 4; ++q) {
                s_[m][q] += __shfl_xor(s_[m][q], off);
                sq[m][q] += __shfl_xor(sq[m][q], off);
            }
    }
    __syncthreads();                     // wl reads done; reuse as reduce buffer
    float* red = (float*)wl;
    if (px == 0) {
#pragma unroll
        for (int m = 0; m < 4; ++m)
#pragma unroll
            for (int q = 0; q < 4; ++q) {
                int c = m * 16 + kg * 4 + q;
                red[wave * 128 + c]      = s_[m][q];
                red[wave * 128 + 64 + c] = sq[m][q];
            }
    }
    __syncthreads();
    if (tid < 128) {
        float t = red[tid] + red[128 + tid] + red[256 + tid] + red[384 + tid];
        atomicAdd(&sums[tid], t);
    }
}

// x f32 NCHW -> padded bf16 image (interior only)
__global__ __launch_bounds__(256)
void xpad_kernel(const float* __restrict__ x, u16* __restrict__ img)
{
    const int b  = blockIdx.y;
    const int y  = blockIdx.x * 2 + (threadIdx.x >> 7);
    const int px = threadIdx.x & 127;
    if (px >= HW) return;
    const float* xr = x + (size_t)b * CH * HW2 + (size_t)y * HW + px;
    u16* op = img + ((size_t)b * SS + 3 + (size_t)y * PW + px) * 64;
#pragma unroll
    for (int cg = 0; cg < 8; ++cg) {
        bf16x8 pk;
#pragma unroll
        for (int j = 0; j < 8; ++j)
            pk[j] = (short)f2b(xr[(size_t)(cg * 8 + j) * HW2]);
        *(bf16x8*)(op + cg * 8) = pk;
    }
}

// in-place BN affine + ReLU on padded image interior
__global__ __launch_bounds__(256)
void post_kernel(u16* __restrict__ img, const float* __restrict__ sb)
{
    const int b  = blockIdx.y;
    const int y  = blockIdx.x * 2 + (threadIdx.x >> 7);
    const int px = threadIdx.x & 127;
    if (px >= HW) return;
    u16* op = img + ((size_t)b * SS + 3 + (size_t)y * PW + px) * 64;
#pragma unroll
    for (int cg = 0; cg < 8; ++cg) {
        bf16x8 v = *(const bf16x8*)(op + cg * 8);
        bf16x8 pk;
#pragma unroll
        for (int j = 0; j < 8; ++j) {
            float t = b2f((u16)v[j]) * sb[cg * 8 + j] + sb[64 + cg * 8 + j];
            pk[j] = (short)f2b(t > 0.f ? t : 0.f);
        }
        *(bf16x8*)(op + cg * 8) = pk;
    }
}

// zero the border slots (p=-3..-1 and y*113+112) of both padded images
__global__ void border_kernel(u16* __restrict__ a, u16* __restrict__ c_)
{
    int t = blockIdx.x * 256 + threadIdx.x;
    if (t >= 2 * NB * 115) return;
    u16* buf = (t >= NB * 115) ? c_ : a;
    int t2 = t % (NB * 115);
    int b = t2 / 115, s = t2 % 115;
    int p = (s < 3) ? (s - 3) : ((s - 3) * PW + HW);
    float4* q = (float4*)(buf + ((size_t)b * SS + 3 + (ptrdiff_t)p) * 64);
#pragma unroll
    for (int i = 0; i < 8; ++i) q[i] = (float4){0.f, 0.f, 0.f, 0.f};
}

// w [b][co][ci][3][3] f32 -> wt [b][tap][co][ci] bf16
__global__ __launch_bounds__(256)
void repack_kernel(const float* __restrict__ w, u16* __restrict__ wt)
{
    int i  = blockIdx.x * 256 + threadIdx.x;   // 1179648 exact
    int ci = i & 63;
    int co = (i >> 6) & 63;
    int bt = i >> 12;
    int t  = bt % 9;
    int b  = bt / 9;
    wt[i] = f2b(w[(((size_t)b * 64 + co) * 64 + ci) * 9 + t]);
}

__global__ void bnparam_kernel(const float* __restrict__ sums,
                               const float* __restrict__ gamma,
                               const float* __restrict__ beta,
                               float* __restrict__ sb)
{
    int c = threadIdx.x;
    if (c < 64) {
        float mean = sums[c] * (1.f / NPC);
        float var  = sums[64 + c] * (1.f / NPC) - mean * mean;
        float sc   = gamma[c] * rsqrtf(var + 1e-5f);
        sb[c]      = sc;
        sb[64 + c] = beta[c] - mean * sc;
    }
}

__global__ void zero_kernel(float* __restrict__ p, int n)
{
    int i = blockIdx.x * 256 + threadIdx.x;
    if (i < n) p[i] = 0.f;
}

// out = relu(bn2(y2pad) + x), NCHW f32 via LDS transpose; one row per block
__global__ __launch_bounds__(256)
void finalize_kernel(const u16* __restrict__ y2, const float* __restrict__ x,
                     const float* __restrict__ sb, float* __restrict__ out)
{
    __shared__ float lt[64][116];
    const int b = blockIdx.y, y = blockIdx.x;
    const int tid = threadIdx.x;
    const u16* rowp = y2 + ((size_t)b * SS + 3 + (size_t)y * PW) * 64;
    {
        const int cg = tid & 7;
        float sc[8], bi[8];
#pragma unroll
        for (int e = 0; e < 8; ++e) { sc[e] = sb[cg * 8 + e]; bi[e] = sb[64 + cg * 8 + e]; }
        for (int t = tid; t < HW * 8; t += 256) {
            int px = t >> 3;
            bf16x8 v = *(const bf16x8*)(rowp + px * 64 + cg * 8);
#pragma unroll
            for (int e = 0; e < 8; ++e)
                lt[cg * 8 + e][px] = b2f((u16)v[e]) * sc[e] + bi[e];
        }
    }
    __syncthreads();
    {
        const int c = tid >> 2, xg = (tid & 3) * 28;
        size_t base = ((size_t)b * CH + c) * HW2 + (size_t)y * HW + xg;
#pragma unroll
        for (int i = 0; i < 7; ++i) {
            float4 xv = *(const float4*)(x + base + i * 4);
            float4 r;
            r.x = fmaxf(lt[c][xg + i * 4 + 0] + xv.x, 0.f);
            r.y = fmaxf(lt[c][xg + i * 4 + 1] + xv.y, 0.f);
            r.z = fmaxf(lt[c][xg + i * 4 + 2] + xv.z, 0.f);
            r.w = fmaxf(lt[c][xg + i * 4 + 3] + xv.w, 0.f);
            *(float4*)(out + base + i * 4) = r;
        }
    }
}

extern "C" void kernel_launch(void* const* d_in, const int* in_sizes, int n_in,
                              void* d_out, int out_size, void* d_ws, size_t ws_size,
                              hipStream_t stream)
{
    const float* x  = (const float*)d_in[0];
    const float* w1 = (const float*)d_in[1];
    const float* w2 = (const float*)d_in[2];
    const float* g1 = (const float*)d_in[3];
    const float* b1 = (const float*)d_in[4];
    const float* g2 = (const float*)d_in[5];
    const float* b2 = (const float*)d_in[6];
    float* out = (float*)d_out;

    // ws: padded image A (xpad, later y2pad) + stats.  51.9MB + 2KB << proven ws.
    char* ws = (char*)d_ws;
    u16*   imgA = (u16*)ws;
    float* st   = (float*)(ws + (size_t)(52u << 20));
    float* sums1 = st, *sums2 = st + 128, *sb1 = st + 256, *sb2 = st + 384;
    // d_out hosts y1pad + repacked weights; all dead before finalize overwrites.
    char*  oc   = (char*)d_out;
    u16*   imgB = (u16*)oc;                            // y1pad (51.9 MB)
    u16*   wt1  = (u16*)(oc + (size_t)(54u << 20));    // 2.25 MB
    u16*   wt2  = (u16*)(oc + (size_t)(58u << 20));    // 2.25 MB

    zero_kernel<<<1, 256, 0, stream>>>(st, 512);
    border_kernel<<<29, 256, 0, stream>>>(imgA, imgB);
    xpad_kernel<<<dim3(56, 32), 256, 0, stream>>>(x, imgA);
    repack_kernel<<<4608, 256, 0, stream>>>(w1, wt1);
    repack_kernel<<<4608, 256, 0, stream>>>(w2, wt2);

    conv_mfma<<<1568, 256, 0, stream>>>(imgA, wt1, imgB, sums1);
    bnparam_kernel<<<1, 64, 0, stream>>>(sums1, g1, b1, sb1);
    post_kernel<<<dim3(56, 32), 256, 0, stream>>>(imgB, sb1);

    conv_mfma<<<1568, 256, 0, stream>>>(imgB, wt2, imgA, sums2);
    bnparam_kernel<<<1, 64, 0, stream>>>(sums2, g2, b2, sb2);

    finalize_kernel<<<dim3(112, 32), 256, 0, stream>>>(imgA, x, sb2, out);
}